// Round 11
// baseline (334.241 us; speedup 1.0000x reference)
//
#include <hip/hip_runtime.h>

// LSS view transform: chunked-gather, d-in-lane run-merged binning, sharded
// cursors (cell-major), cell-major atomic accumulator, fused prep kernel.
// out[b,c,cell] = sum_{(pix,d)->cell} img[b,c,pix] * dp[b,d,pix]
// Round-11 changes:
//  - gather: XCD-aware batch split (entries are cell-sorted -> first offs[NCELL]
//    entries are batch 0; blocks with blockIdx%8<4 take b0 chunks, others b1 ->
//    each XCD's L2 only caches its 3.9MB img half).
//  - entries packed uint2{key, fp32 weight} (ws is ~256MB; one 8B line per
//    entry in fill, one staging load in gather, absmax back to ~0.004).
//  - hist2 cell-major [cell][shard]: reduce = contiguous int4 row sums,
//    shardbase = contiguous 256B r/w per thread (was 64x128KB-strided).
constexpr int IMG_H = 48, IMG_W = 160;
constexpr int HW    = IMG_H * IMG_W;          // 7680
constexpr int BEV_H = 128, BEV_W = 128;
constexpr int NCELL = BEV_H * BEV_W;          // 16384 per batch
constexpr int C_DIM = 128, D_DIM = 64, B_DIM = 2;
constexpr int NCELL_TOT = B_DIM * NCELL;      // 32768
constexpr int NPIX_TOT  = B_DIM * HW;         // 15360
constexpr int NPTS      = NPIX_TOT * D_DIM;   // 983040
constexpr int CHUNK = 64;
constexpr int NSHARD = 64;
constexpr float X_MIN = -51.2f, Y_MIN = -51.2f;
constexpr float RES_X = 102.4f / 128.0f;
constexpr float RES_Y = 102.4f / 128.0f;

// ---- ws layout (4-byte words), ~45 MB total (ws is ~256 MB) ----
constexpr size_t WS_IMG_T = 0;                                      // float[B*HW*C] 1966080
constexpr size_t WS_DP_T  = WS_IMG_T + (size_t)B_DIM * HW * C_DIM;  // float[B*HW*D] 983040
constexpr size_t WS_HIST2 = WS_DP_T + (size_t)B_DIM * HW * D_DIM;   // int[32768*NSHARD] cell-major
constexpr size_t WS_OUT_T = WS_HIST2 + (size_t)NCELL_TOT * NSHARD;  // float[NCELL_TOT*C] (adjacent -> fused memset)
constexpr size_t WS_HIST  = WS_OUT_T + (size_t)NCELL_TOT * C_DIM;   // int[32768]
constexpr size_t WS_OFFS  = WS_HIST + NCELL_TOT;                    // int[32769] (+3 pad)
constexpr size_t WS_ENT   = WS_OFFS + NCELL_TOT + 4;                // uint2[NPTS] (offset is even -> 8B aligned)

__device__ inline void make_ray(const float* __restrict__ K, int b, float gx, float gy,
                                float& rx, float& ry, float& rz) {
    const float* Kb = K + b * 9;
    const float a00 = Kb[0], a01 = Kb[1], a02 = Kb[2];
    const float a10 = Kb[3], a11 = Kb[4], a12 = Kb[5];
    const float a20 = Kb[6], a21 = Kb[7], a22 = Kb[8];
    const float det = a00 * (a11 * a22 - a12 * a21)
                    - a01 * (a10 * a22 - a12 * a20)
                    + a02 * (a10 * a21 - a11 * a20);
    const float inv = 1.0f / det;
    const float i00 =  (a11 * a22 - a12 * a21) * inv;
    const float i01 = -(a01 * a22 - a02 * a21) * inv;
    const float i02 =  (a01 * a12 - a02 * a11) * inv;
    const float i10 = -(a10 * a22 - a12 * a20) * inv;
    const float i11 =  (a00 * a22 - a02 * a20) * inv;
    const float i12 = -(a00 * a12 - a02 * a10) * inv;
    const float i20 =  (a10 * a21 - a11 * a20) * inv;
    const float i21 = -(a00 * a21 - a01 * a20) * inv;
    const float i22 =  (a00 * a11 - a01 * a10) * inv;
    rx = i00 * gx + i01 * gy + i02;
    ry = i10 * gx + i11 * gy + i12;
    rz = i20 * gx + i21 * gy + i22;
}

// Global cell id (b*NCELL + cell) or -1 for ray (b,pix) at depth bin d.
__device__ inline int gcell_ray(int b, int pix, int d,
                                const float* __restrict__ dv,
                                const float* __restrict__ K,
                                const float* __restrict__ T) {
    const int h = pix / IMG_W, w = pix % IMG_W;
    float rx, ry, rz;
    make_ray(K, b, (float)w, (float)h, rx, ry, rz);
    const float* Tb = T + b * 16;
    const float dep = dv[d];                       // lane-coalesced (lane == d)
    const float px = dep * rx, py = dep * ry, pz = dep * rz;
    const float x = Tb[0] * px + Tb[1] * py + Tb[2]  * pz + Tb[3];
    const float y = Tb[4] * px + Tb[5] * py + Tb[6]  * pz + Tb[7];
    const float z = Tb[8] * px + Tb[9] * py + Tb[10] * pz + Tb[11];
    const int bx = (int)((x - X_MIN) / RES_X);     // truncate-toward-zero == astype(int32)
    const int by = (int)((y - Y_MIN) / RES_Y);
    const bool valid = (bx >= 0) && (bx < BEV_W) && (by >= 0) && (by < BEV_H) && (z > 0.0f);
    return valid ? (b * NCELL + by * BEV_W + bx) : -1;
}

// Run structure across the wave (lanes = consecutive d of one ray).
struct RunInfo { int leader_idx; bool is_tail; };
__device__ inline RunInfo wave_runs_d(int gcell, int lane) {
    const int left = __shfl_up(gcell, 1);          // width 64
    const bool is_leader = (lane == 0) || (left != gcell);
    const unsigned long long lmask = __ballot(is_leader);
    const unsigned long long below =
        lmask & ((lane == 63) ? ~0ULL : ((1ULL << (lane + 1)) - 1ULL));
    RunInfo r;
    r.leader_idx = 63 - __clzll((long long)below);
    r.is_tail = (lane == 63) || ((lmask >> (lane + 1)) & 1ULL);
    return r;
}

__device__ inline int shard_of(int pix) { return (pix ^ (pix >> 6)) & (NSHARD - 1); }

// ---- K1 fused prep: img transpose + dp transpose + run count ----
constexpr int NB_IMG = (HW / 32) * (C_DIM / 32) * B_DIM;   // 1920
constexpr int NB_DP  = (HW / 32) * (D_DIM / 32) * B_DIM;   // 960
constexpr int NB_CNT = NPTS / 256;                         // 3840
__global__ __launch_bounds__(256) void k_prep(const float* __restrict__ img,
                                              const float* __restrict__ dp,
                                              const float* __restrict__ dv,
                                              const float* __restrict__ K,
                                              const float* __restrict__ T,
                                              float* __restrict__ img_t,
                                              float* __restrict__ dp_t,
                                              int* __restrict__ hist2) {
    int bid = blockIdx.x;
    if (bid < NB_IMG + NB_DP) {
        // tiled 32x32 transpose: src[b, r, pix] -> dst[b, pix, r]
        const float* src; float* dst; int rows;
        if (bid < NB_IMG) { src = img; dst = img_t; rows = C_DIM; }
        else              { bid -= NB_IMG; src = dp; dst = dp_t; rows = D_DIM; }
        const int tiles_c = rows / 32;
        const int b = bid / ((HW / 32) * tiles_c);
        const int r = bid % ((HW / 32) * tiles_c);
        const int ctile = r / (HW / 32), ptile = r % (HW / 32);
        __shared__ float tile[32][33];
        const int tx = threadIdx.x & 31, ty = threadIdx.x >> 5;   // (32, 8)
        const int pix0 = ptile * 32, c0 = ctile * 32;
        #pragma unroll
        for (int j = 0; j < 32; j += 8)
            tile[ty + j][tx] = src[((size_t)(b * rows + c0 + ty + j)) * HW + pix0 + tx];
        __syncthreads();
        #pragma unroll
        for (int j = 0; j < 32; j += 8)
            dst[((size_t)(b * HW + pix0 + ty + j)) * rows + c0 + tx] = tile[tx][ty + j];
    } else {
        // count merged runs; wave = one ray, lane = depth bin
        const int tid = (bid - NB_IMG - NB_DP) * 256 + threadIdx.x;   // < NPTS
        const int lane = threadIdx.x & 63;                            // = d
        const int wid = tid >> 6;                                     // ray id
        const int b = wid / HW, pix = wid % HW;
        const int gcell = gcell_ray(b, pix, lane, dv, K, T);
        const RunInfo ri = wave_runs_d(gcell, lane);
        if (ri.is_tail && gcell >= 0)
            atomicAdd(&hist2[(size_t)gcell * NSHARD + shard_of(pix)], 1);
    }
}

// ---- K2: reduce shards -> per-cell totals (contiguous int4 row sums) ----
__global__ __launch_bounds__(256) void k_reduce(const int* __restrict__ hist2,
                                                int* __restrict__ hist) {
    const int cell = blockIdx.x * 256 + threadIdx.x;  // 128 blocks exact
    const int4* row = reinterpret_cast<const int4*>(hist2 + (size_t)cell * NSHARD);
    int s = 0;
    #pragma unroll
    for (int k = 0; k < NSHARD / 4; ++k) {
        const int4 v = row[k];
        s += v.x + v.y + v.z + v.w;
    }
    hist[cell] = s;
}

// ---- K3: exclusive prefix scan over hist[32768] -> offs[32769] ----
__global__ __launch_bounds__(1024) void k_scan(const int* __restrict__ hist,
                                               int* __restrict__ offs) {
    __shared__ int lds[1024];
    const int t = threadIdx.x;
    int h[32];
    int s = 0;
    const int base = t * 32;
    const int4* hv = reinterpret_cast<const int4*>(hist + base);
    #pragma unroll
    for (int k = 0; k < 8; ++k) {
        const int4 v = hv[k];
        h[4 * k] = v.x; h[4 * k + 1] = v.y; h[4 * k + 2] = v.z; h[4 * k + 3] = v.w;
        s += v.x + v.y + v.z + v.w;
    }
    lds[t] = s;
    __syncthreads();
    for (int off = 1; off < 1024; off <<= 1) {
        int v = (t >= off) ? lds[t - off] : 0;
        __syncthreads();
        lds[t] += v;
        __syncthreads();
    }
    int run = lds[t] - s;
    #pragma unroll
    for (int k = 0; k < 32; ++k) {
        offs[base + k] = run;
        run += h[k];
    }
    if (t == 1023) offs[NCELL_TOT] = lds[1023];
}

// ---- K4: per-cell shard prefix; hist2 becomes cursor bases in place
// (contiguous 256B read + 256B write per thread). ----
__global__ __launch_bounds__(256) void k_shardbase(int* __restrict__ hist2,
                                                   const int* __restrict__ offs) {
    const int cell = blockIdx.x * 256 + threadIdx.x;  // 128 blocks exact
    int* row = hist2 + (size_t)cell * NSHARD;
    int run = offs[cell];
    #pragma unroll
    for (int sh = 0; sh < NSHARD; ++sh) {
        const int cnt = row[sh];
        row[sh] = run;
        run += cnt;
    }
}

// ---- K5: fill merged entries. Wave = one ray; segmented inclusive scan of dp
// over equal-cell runs; run tail emits packed uint2{key, fp32 weight}. ----
__global__ __launch_bounds__(256) void k_fill(const float* __restrict__ dp_t,
                                              const float* __restrict__ dv,
                                              const float* __restrict__ K,
                                              const float* __restrict__ T,
                                              int* __restrict__ cursor2,   // = hist2 (bases)
                                              uint2* __restrict__ ent) {
    const int tid = blockIdx.x * 256 + threadIdx.x;   // < NPTS
    const int lane = threadIdx.x & 63;                // = d
    const int wid = tid >> 6;                         // ray id
    const int b = wid / HW, pix = wid % HW;
    const int gcell = gcell_ray(b, pix, lane, dv, K, T);
    const RunInfo ri = wave_runs_d(gcell, lane);
    const float p = dp_t[((size_t)(b * HW + pix)) * D_DIM + lane];   // lane-contiguous
    // segmented inclusive scan (Hillis-Steele with head clamp)
    float val = p;
    #pragma unroll
    for (int dlt = 1; dlt < 64; dlt <<= 1) {
        const float up = __shfl_up(val, dlt);
        val = (lane - dlt >= ri.leader_idx) ? val + up : val;
    }
    if (ri.is_tail && gcell >= 0) {
        const int slot = atomicAdd(&cursor2[(size_t)gcell * NSHARD + shard_of(pix)], 1);
        ent[slot] = make_uint2((unsigned)((gcell << 13) | pix), __float_as_uint(val));
    }
}

// ---- K6: chunked segmented reduction. One 64-entry chunk per 64-thread block;
// thread = 2 channels (float2); flushes to cell-major out_t. XCD-aware split:
// entries are cell-sorted, so [0, offs[NCELL]) is batch 0. Blocks with
// blockIdx%8 < 4 process b0 chunks, others b1 -> each XCD's L2 caches only
// its 3.9 MB img half. ----
__global__ __launch_bounds__(64) void k_gather(
    const float* __restrict__ img_t,
    const int* __restrict__ offs,     // offs[NCELL]=b0 count, offs[NCELL_TOT]=total
    const uint2* __restrict__ ent,
    float* __restrict__ out_t)
{
    const int total = offs[NCELL_TOT];
    const int n0 = offs[NCELL];
    const int nch0 = (n0 + CHUNK - 1) / CHUNK;
    const int nch_tot = (total + CHUNK - 1) / CHUNK;

    const int xcd = blockIdx.x & 7;
    const int slot = blockIdx.x >> 3;                 // 0..1919
    int chunk;
    if (xcd < 4) {
        chunk = slot * 4 + xcd;                       // covers [0, 7680)
        if (chunk >= nch0) return;
    } else {
        chunk = nch0 + slot * 4 + (xcd - 4);          // covers [nch0, nch0+7680)
        if (chunk >= nch_tot) return;
    }
    const int base = chunk * CHUNK;

    __shared__ int   s_key[CHUNK];
    __shared__ float s_w[CHUNK];
    {
        const int i = threadIdx.x;                    // 64 threads, CHUNK=64
        const int idx = min(base + i, total - 1);
        const uint2 e = ent[idx];
        s_key[i] = (int)e.x;                          // pad = dup of last key
        s_w[i]   = (base + i < total) ? __uint_as_float(e.y) : 0.0f;
    }
    __syncthreads();

    const int c2 = threadIdx.x * 2;                   // channels c2, c2+1
    int prev = s_key[0] >> 13;
    float2 acc = make_float2(0.0f, 0.0f);
    #pragma unroll 8
    for (int k = 0; k < CHUNK; ++k) {                 // static trip count -> pipelined
        const int key = s_key[k];                     // LDS broadcast (wave-uniform)
        const float wgt = s_w[k];
        const int gcell = key >> 13;
        const int pix = key & 8191;
        const int b = gcell >> 14;
        const float2 v = *reinterpret_cast<const float2*>(
            &img_t[((size_t)(b * HW + pix)) * C_DIM + c2]);   // 8B/lane, coalesced
        if (gcell != prev) {                          // wave-uniform branch
            float* o = &out_t[(size_t)prev * C_DIM + c2];
            atomicAdd(o, acc.x);
            atomicAdd(o + 1, acc.y);
            acc = make_float2(0.0f, 0.0f);
            prev = gcell;
        }
        acc.x = fmaf(v.x, wgt, acc.x);
        acc.y = fmaf(v.y, wgt, acc.y);
    }
    float* o = &out_t[(size_t)prev * C_DIM + c2];
    atomicAdd(o, acc.x);
    atomicAdd(o + 1, acc.y);
}

// ---- K7: untranspose out_t[b][cell][c] -> out[b][c][cell] ----
__global__ __launch_bounds__(256) void k_untranspose(const float* __restrict__ out_t,
                                                     float* __restrict__ out) {
    __shared__ float tile[32][33];
    const int b = blockIdx.z;
    const int tx = threadIdx.x, ty = threadIdx.y;      // block (32, 8)
    const int cell0 = blockIdx.x * 32, c0 = blockIdx.y * 32;
    const float* src = out_t + (size_t)b * NCELL * C_DIM;
    #pragma unroll
    for (int j = 0; j < 32; j += 8)
        tile[ty + j][tx] = src[((size_t)(cell0 + ty + j)) * C_DIM + c0 + tx];
    __syncthreads();
    #pragma unroll
    for (int j = 0; j < 32; j += 8)
        out[((size_t)(b * C_DIM + c0 + ty + j)) * NCELL + cell0 + tx] = tile[tx][ty + j];
}

extern "C" void kernel_launch(void* const* d_in, const int* in_sizes, int n_in,
                              void* d_out, int out_size, void* d_ws, size_t ws_size,
                              hipStream_t stream) {
    const float* img = (const float*)d_in[0];
    const float* dp  = (const float*)d_in[1];
    const float* dv  = (const float*)d_in[2];
    const float* K   = (const float*)d_in[3];
    const float* T   = (const float*)d_in[4];
    float* out = (float*)d_out;

    float* ws_f   = (float*)d_ws;
    float* img_t  = ws_f + WS_IMG_T;
    float* dp_t   = ws_f + WS_DP_T;
    int*   hist2  = (int*)d_ws + WS_HIST2;
    float* out_t  = ws_f + WS_OUT_T;
    int*   hist   = (int*)d_ws + WS_HIST;
    int*   offs   = (int*)d_ws + WS_OFFS;
    uint2* ent    = (uint2*)((int*)d_ws + WS_ENT);

    // hist2 and out_t adjacent -> one fused memset (8 MB + 16 MB)
    hipMemsetAsync(hist2, 0,
                   ((size_t)NCELL_TOT * NSHARD + (size_t)NCELL_TOT * C_DIM) * sizeof(int),
                   stream);

    k_prep<<<NB_IMG + NB_DP + NB_CNT, 256, 0, stream>>>(img, dp, dv, K, T,
                                                        img_t, dp_t, hist2);
    k_reduce<<<NCELL_TOT / 256, 256, 0, stream>>>(hist2, hist);
    k_scan<<<1, 1024, 0, stream>>>(hist, offs);
    k_shardbase<<<NCELL_TOT / 256, 256, 0, stream>>>(hist2, offs);
    k_fill<<<NPTS / 256, 256, 0, stream>>>(dp_t, dv, K, T, hist2, ent);
    k_gather<<<NPTS / CHUNK, 64, 0, stream>>>(img_t, offs, ent, out_t);
    k_untranspose<<<dim3(NCELL / 32, C_DIM / 32, B_DIM), dim3(32, 8), 0, stream>>>(
        out_t, out);
}

// Round 12
// 168.912 us; speedup vs baseline: 1.9788x; 1.9788x over previous
//
#include <hip/hip_runtime.h>

// LSS view transform: chunked-gather, d-in-lane run-merged binning, 64-way
// SHARD-MAJOR sharded cursors, cell-major atomic accumulator, fused prep.
// out[b,c,cell] = sum_{(pix,d)->cell} img[b,c,pix] * dp[b,d,pix]
// Round-12: revert round-11's cell-major cursor layout (it put a hot cell's
// 64 shard counters into 4 adjacent lines -> re-serialized the hot atomics,
// fill 25->105 us). Shard-major [shard][cell] keeps hot-cell counters 128KB
// apart (proven rounds 5-10). Kept from round 11: packed uint2{key, fp32 w}
// entries (absmax 0.004) and XCD-aware batch-split gather.
constexpr int IMG_H = 48, IMG_W = 160;
constexpr int HW    = IMG_H * IMG_W;          // 7680
constexpr int BEV_H = 128, BEV_W = 128;
constexpr int NCELL = BEV_H * BEV_W;          // 16384 per batch
constexpr int C_DIM = 128, D_DIM = 64, B_DIM = 2;
constexpr int NCELL_TOT = B_DIM * NCELL;      // 32768
constexpr int NPIX_TOT  = B_DIM * HW;         // 15360
constexpr int NPTS      = NPIX_TOT * D_DIM;   // 983040
constexpr int CHUNK = 64;
constexpr int NSHARD = 64;
constexpr float X_MIN = -51.2f, Y_MIN = -51.2f;
constexpr float RES_X = 102.4f / 128.0f;
constexpr float RES_Y = 102.4f / 128.0f;

// ---- ws layout (4-byte words), ~45 MB total (ws is ~256 MB) ----
constexpr size_t WS_IMG_T = 0;                                      // float[B*HW*C] 1966080
constexpr size_t WS_DP_T  = WS_IMG_T + (size_t)B_DIM * HW * C_DIM;  // float[B*HW*D] 983040
constexpr size_t WS_HIST2 = WS_DP_T + (size_t)B_DIM * HW * D_DIM;   // int[NSHARD][NCELL_TOT] shard-major
constexpr size_t WS_OUT_T = WS_HIST2 + (size_t)NSHARD * NCELL_TOT;  // float[NCELL_TOT*C] (adjacent -> fused memset)
constexpr size_t WS_HIST  = WS_OUT_T + (size_t)NCELL_TOT * C_DIM;   // int[32768]
constexpr size_t WS_OFFS  = WS_HIST + NCELL_TOT;                    // int[32769] (+3 pad)
constexpr size_t WS_ENT   = WS_OFFS + NCELL_TOT + 4;                // uint2[NPTS] (even offset -> 8B aligned)

__device__ inline void make_ray(const float* __restrict__ K, int b, float gx, float gy,
                                float& rx, float& ry, float& rz) {
    const float* Kb = K + b * 9;
    const float a00 = Kb[0], a01 = Kb[1], a02 = Kb[2];
    const float a10 = Kb[3], a11 = Kb[4], a12 = Kb[5];
    const float a20 = Kb[6], a21 = Kb[7], a22 = Kb[8];
    const float det = a00 * (a11 * a22 - a12 * a21)
                    - a01 * (a10 * a22 - a12 * a20)
                    + a02 * (a10 * a21 - a11 * a20);
    const float inv = 1.0f / det;
    const float i00 =  (a11 * a22 - a12 * a21) * inv;
    const float i01 = -(a01 * a22 - a02 * a21) * inv;
    const float i02 =  (a01 * a12 - a02 * a11) * inv;
    const float i10 = -(a10 * a22 - a12 * a20) * inv;
    const float i11 =  (a00 * a22 - a02 * a20) * inv;
    const float i12 = -(a00 * a12 - a02 * a10) * inv;
    const float i20 =  (a10 * a21 - a11 * a20) * inv;
    const float i21 = -(a00 * a21 - a01 * a20) * inv;
    const float i22 =  (a00 * a11 - a01 * a10) * inv;
    rx = i00 * gx + i01 * gy + i02;
    ry = i10 * gx + i11 * gy + i12;
    rz = i20 * gx + i21 * gy + i22;
}

// Global cell id (b*NCELL + cell) or -1 for ray (b,pix) at depth bin d.
__device__ inline int gcell_ray(int b, int pix, int d,
                                const float* __restrict__ dv,
                                const float* __restrict__ K,
                                const float* __restrict__ T) {
    const int h = pix / IMG_W, w = pix % IMG_W;
    float rx, ry, rz;
    make_ray(K, b, (float)w, (float)h, rx, ry, rz);
    const float* Tb = T + b * 16;
    const float dep = dv[d];                       // lane-coalesced (lane == d)
    const float px = dep * rx, py = dep * ry, pz = dep * rz;
    const float x = Tb[0] * px + Tb[1] * py + Tb[2]  * pz + Tb[3];
    const float y = Tb[4] * px + Tb[5] * py + Tb[6]  * pz + Tb[7];
    const float z = Tb[8] * px + Tb[9] * py + Tb[10] * pz + Tb[11];
    const int bx = (int)((x - X_MIN) / RES_X);     // truncate-toward-zero == astype(int32)
    const int by = (int)((y - Y_MIN) / RES_Y);
    const bool valid = (bx >= 0) && (bx < BEV_W) && (by >= 0) && (by < BEV_H) && (z > 0.0f);
    return valid ? (b * NCELL + by * BEV_W + bx) : -1;
}

// Run structure across the wave (lanes = consecutive d of one ray).
struct RunInfo { int leader_idx; bool is_tail; };
__device__ inline RunInfo wave_runs_d(int gcell, int lane) {
    const int left = __shfl_up(gcell, 1);          // width 64
    const bool is_leader = (lane == 0) || (left != gcell);
    const unsigned long long lmask = __ballot(is_leader);
    const unsigned long long below =
        lmask & ((lane == 63) ? ~0ULL : ((1ULL << (lane + 1)) - 1ULL));
    RunInfo r;
    r.leader_idx = 63 - __clzll((long long)below);
    r.is_tail = (lane == 63) || ((lmask >> (lane + 1)) & 1ULL);
    return r;
}

__device__ inline int shard_of(int pix) { return (pix ^ (pix >> 6)) & (NSHARD - 1); }

// ---- K1 fused prep: img transpose + dp transpose + run count ----
constexpr int NB_IMG = (HW / 32) * (C_DIM / 32) * B_DIM;   // 1920
constexpr int NB_DP  = (HW / 32) * (D_DIM / 32) * B_DIM;   // 960
constexpr int NB_CNT = NPTS / 256;                         // 3840
__global__ __launch_bounds__(256) void k_prep(const float* __restrict__ img,
                                              const float* __restrict__ dp,
                                              const float* __restrict__ dv,
                                              const float* __restrict__ K,
                                              const float* __restrict__ T,
                                              float* __restrict__ img_t,
                                              float* __restrict__ dp_t,
                                              int* __restrict__ hist2) {
    int bid = blockIdx.x;
    if (bid < NB_IMG + NB_DP) {
        // tiled 32x32 transpose: src[b, r, pix] -> dst[b, pix, r]
        const float* src; float* dst; int rows;
        if (bid < NB_IMG) { src = img; dst = img_t; rows = C_DIM; }
        else              { bid -= NB_IMG; src = dp; dst = dp_t; rows = D_DIM; }
        const int tiles_c = rows / 32;
        const int b = bid / ((HW / 32) * tiles_c);
        const int r = bid % ((HW / 32) * tiles_c);
        const int ctile = r / (HW / 32), ptile = r % (HW / 32);
        __shared__ float tile[32][33];
        const int tx = threadIdx.x & 31, ty = threadIdx.x >> 5;   // (32, 8)
        const int pix0 = ptile * 32, c0 = ctile * 32;
        #pragma unroll
        for (int j = 0; j < 32; j += 8)
            tile[ty + j][tx] = src[((size_t)(b * rows + c0 + ty + j)) * HW + pix0 + tx];
        __syncthreads();
        #pragma unroll
        for (int j = 0; j < 32; j += 8)
            dst[((size_t)(b * HW + pix0 + ty + j)) * rows + c0 + tx] = tile[tx][ty + j];
    } else {
        // count merged runs; wave = one ray, lane = depth bin
        const int tid = (bid - NB_IMG - NB_DP) * 256 + threadIdx.x;   // < NPTS
        const int lane = threadIdx.x & 63;                            // = d
        const int wid = tid >> 6;                                     // ray id
        const int b = wid / HW, pix = wid % HW;
        const int gcell = gcell_ray(b, pix, lane, dv, K, T);
        const RunInfo ri = wave_runs_d(gcell, lane);
        if (ri.is_tail && gcell >= 0)
            atomicAdd(&hist2[(size_t)shard_of(pix) * NCELL_TOT + gcell], 1);
    }
}

// ---- K2: reduce shards -> per-cell totals (strided; proven cheap) ----
__global__ __launch_bounds__(256) void k_reduce(const int* __restrict__ hist2,
                                                int* __restrict__ hist) {
    const int cell = blockIdx.x * 256 + threadIdx.x;  // 128 blocks exact
    int s = 0;
    #pragma unroll
    for (int sh = 0; sh < NSHARD; ++sh)
        s += hist2[(size_t)sh * NCELL_TOT + cell];
    hist[cell] = s;
}

// ---- K3: exclusive prefix scan over hist[32768] -> offs[32769] ----
__global__ __launch_bounds__(1024) void k_scan(const int* __restrict__ hist,
                                               int* __restrict__ offs) {
    __shared__ int lds[1024];
    const int t = threadIdx.x;
    int h[32];
    int s = 0;
    const int base = t * 32;
    const int4* hv = reinterpret_cast<const int4*>(hist + base);
    #pragma unroll
    for (int k = 0; k < 8; ++k) {
        const int4 v = hv[k];
        h[4 * k] = v.x; h[4 * k + 1] = v.y; h[4 * k + 2] = v.z; h[4 * k + 3] = v.w;
        s += v.x + v.y + v.z + v.w;
    }
    lds[t] = s;
    __syncthreads();
    for (int off = 1; off < 1024; off <<= 1) {
        int v = (t >= off) ? lds[t - off] : 0;
        __syncthreads();
        lds[t] += v;
        __syncthreads();
    }
    int run = lds[t] - s;
    #pragma unroll
    for (int k = 0; k < 32; ++k) {
        offs[base + k] = run;
        run += h[k];
    }
    if (t == 1023) offs[NCELL_TOT] = lds[1023];
}

// ---- K4: per-cell shard prefix; hist2 becomes cursor bases in place ----
__global__ __launch_bounds__(256) void k_shardbase(int* __restrict__ hist2,
                                                   const int* __restrict__ offs) {
    const int cell = blockIdx.x * 256 + threadIdx.x;  // 128 blocks exact
    int run = offs[cell];
    #pragma unroll
    for (int sh = 0; sh < NSHARD; ++sh) {
        const size_t idx = (size_t)sh * NCELL_TOT + cell;
        const int cnt = hist2[idx];
        hist2[idx] = run;
        run += cnt;
    }
}

// ---- K5: fill merged entries. Wave = one ray; segmented inclusive scan of dp
// over equal-cell runs; run tail emits packed uint2{key, fp32 weight}. ----
__global__ __launch_bounds__(256) void k_fill(const float* __restrict__ dp_t,
                                              const float* __restrict__ dv,
                                              const float* __restrict__ K,
                                              const float* __restrict__ T,
                                              int* __restrict__ cursor2,   // = hist2 (bases)
                                              uint2* __restrict__ ent) {
    const int tid = blockIdx.x * 256 + threadIdx.x;   // < NPTS
    const int lane = threadIdx.x & 63;                // = d
    const int wid = tid >> 6;                         // ray id
    const int b = wid / HW, pix = wid % HW;
    const int gcell = gcell_ray(b, pix, lane, dv, K, T);
    const RunInfo ri = wave_runs_d(gcell, lane);
    const float p = dp_t[((size_t)(b * HW + pix)) * D_DIM + lane];   // lane-contiguous
    // segmented inclusive scan (Hillis-Steele with head clamp)
    float val = p;
    #pragma unroll
    for (int dlt = 1; dlt < 64; dlt <<= 1) {
        const float up = __shfl_up(val, dlt);
        val = (lane - dlt >= ri.leader_idx) ? val + up : val;
    }
    if (ri.is_tail && gcell >= 0) {
        const int slot = atomicAdd(&cursor2[(size_t)shard_of(pix) * NCELL_TOT + gcell], 1);
        ent[slot] = make_uint2((unsigned)((gcell << 13) | pix), __float_as_uint(val));
    }
}

// ---- K6: chunked segmented reduction. One 64-entry chunk per 64-thread block;
// thread = 2 channels (float2); flushes to cell-major out_t. XCD-aware split:
// entries are cell-sorted, so [0, offs[NCELL]) is batch 0. Blocks with
// blockIdx%8 < 4 process b0 chunks, others b1. ----
__global__ __launch_bounds__(64) void k_gather(
    const float* __restrict__ img_t,
    const int* __restrict__ offs,     // offs[NCELL]=b0 count, offs[NCELL_TOT]=total
    const uint2* __restrict__ ent,
    float* __restrict__ out_t)
{
    const int total = offs[NCELL_TOT];
    const int n0 = offs[NCELL];
    const int nch0 = (n0 + CHUNK - 1) / CHUNK;
    const int nch_tot = (total + CHUNK - 1) / CHUNK;

    const int xcd = blockIdx.x & 7;
    const int slot = blockIdx.x >> 3;                 // 0..1919
    int chunk;
    if (xcd < 4) {
        chunk = slot * 4 + xcd;                       // covers [0, 7680)
        if (chunk >= nch0) return;
    } else {
        chunk = nch0 + slot * 4 + (xcd - 4);          // covers [nch0, nch0+7680)
        if (chunk >= nch_tot) return;
    }
    const int base = chunk * CHUNK;

    __shared__ int   s_key[CHUNK];
    __shared__ float s_w[CHUNK];
    {
        const int i = threadIdx.x;                    // 64 threads, CHUNK=64
        const int idx = min(base + i, total - 1);
        const uint2 e = ent[idx];
        s_key[i] = (int)e.x;                          // pad = dup of last key
        s_w[i]   = (base + i < total) ? __uint_as_float(e.y) : 0.0f;
    }
    __syncthreads();

    const int c2 = threadIdx.x * 2;                   // channels c2, c2+1
    int prev = s_key[0] >> 13;
    float2 acc = make_float2(0.0f, 0.0f);
    #pragma unroll 8
    for (int k = 0; k < CHUNK; ++k) {                 // static trip count -> pipelined
        const int key = s_key[k];                     // LDS broadcast (wave-uniform)
        const float wgt = s_w[k];
        const int gcell = key >> 13;
        const int pix = key & 8191;
        const int b = gcell >> 14;
        const float2 v = *reinterpret_cast<const float2*>(
            &img_t[((size_t)(b * HW + pix)) * C_DIM + c2]);   // 8B/lane, coalesced
        if (gcell != prev) {                          // wave-uniform branch
            float* o = &out_t[(size_t)prev * C_DIM + c2];
            atomicAdd(o, acc.x);
            atomicAdd(o + 1, acc.y);
            acc = make_float2(0.0f, 0.0f);
            prev = gcell;
        }
        acc.x = fmaf(v.x, wgt, acc.x);
        acc.y = fmaf(v.y, wgt, acc.y);
    }
    float* o = &out_t[(size_t)prev * C_DIM + c2];
    atomicAdd(o, acc.x);
    atomicAdd(o + 1, acc.y);
}

// ---- K7: untranspose out_t[b][cell][c] -> out[b][c][cell] ----
__global__ __launch_bounds__(256) void k_untranspose(const float* __restrict__ out_t,
                                                     float* __restrict__ out) {
    __shared__ float tile[32][33];
    const int b = blockIdx.z;
    const int tx = threadIdx.x, ty = threadIdx.y;      // block (32, 8)
    const int cell0 = blockIdx.x * 32, c0 = blockIdx.y * 32;
    const float* src = out_t + (size_t)b * NCELL * C_DIM;
    #pragma unroll
    for (int j = 0; j < 32; j += 8)
        tile[ty + j][tx] = src[((size_t)(cell0 + ty + j)) * C_DIM + c0 + tx];
    __syncthreads();
    #pragma unroll
    for (int j = 0; j < 32; j += 8)
        out[((size_t)(b * C_DIM + c0 + ty + j)) * NCELL + cell0 + tx] = tile[tx][ty + j];
}

extern "C" void kernel_launch(void* const* d_in, const int* in_sizes, int n_in,
                              void* d_out, int out_size, void* d_ws, size_t ws_size,
                              hipStream_t stream) {
    const float* img = (const float*)d_in[0];
    const float* dp  = (const float*)d_in[1];
    const float* dv  = (const float*)d_in[2];
    const float* K   = (const float*)d_in[3];
    const float* T   = (const float*)d_in[4];
    float* out = (float*)d_out;

    float* ws_f   = (float*)d_ws;
    float* img_t  = ws_f + WS_IMG_T;
    float* dp_t   = ws_f + WS_DP_T;
    int*   hist2  = (int*)d_ws + WS_HIST2;
    float* out_t  = ws_f + WS_OUT_T;
    int*   hist   = (int*)d_ws + WS_HIST;
    int*   offs   = (int*)d_ws + WS_OFFS;
    uint2* ent    = (uint2*)((int*)d_ws + WS_ENT);

    // hist2 and out_t adjacent -> one fused memset (8 MB + 16 MB)
    hipMemsetAsync(hist2, 0,
                   ((size_t)NSHARD * NCELL_TOT + (size_t)NCELL_TOT * C_DIM) * sizeof(int),
                   stream);

    k_prep<<<NB_IMG + NB_DP + NB_CNT, 256, 0, stream>>>(img, dp, dv, K, T,
                                                        img_t, dp_t, hist2);
    k_reduce<<<NCELL_TOT / 256, 256, 0, stream>>>(hist2, hist);
    k_scan<<<1, 1024, 0, stream>>>(hist, offs);
    k_shardbase<<<NCELL_TOT / 256, 256, 0, stream>>>(hist2, offs);
    k_fill<<<NPTS / 256, 256, 0, stream>>>(dp_t, dv, K, T, hist2, ent);
    k_gather<<<NPTS / CHUNK, 64, 0, stream>>>(img_t, offs, ent, out_t);
    k_untranspose<<<dim3(NCELL / 32, C_DIM / 32, B_DIM), dim3(32, 8), 0, stream>>>(
        out_t, out);
}